// Round 2
// baseline (658.873 us; speedup 1.0000x reference)
//
#include <hip/hip_runtime.h>
#include <math.h>

#define B_TOTAL 65536
#define IN_DIM 512
#define HID_DIM 512
#define FAN1 1024
#define NQ 8
#define NGATES 4

__device__ __forceinline__ float fast_rcp(float x) {
    return __builtin_amdgcn_rcpf(x);  // v_rcp_f32, ~1 ulp
}
__device__ __forceinline__ float sigmoid_f(float v) {
    return fast_rcp(1.0f + __expf(-v));
}
__device__ __forceinline__ float tanh_fast(float v) {
    // 1 - 2/(e^{2v}+1); saturates to +/-1 for |v| large.
    return 1.0f - 2.0f * fast_rcp(__expf(2.0f * v) + 1.0f);
}

// ---------------------------------------------------------------------------
// Fused kernel. Block = 256 threads (4 waves) owns 64 batch rows.
//
// Phase A (z = tanh([x,h]@W1^T + b1)):
//   wave g == gate g computes q=0..7 for all 64 rows (row = lane, 8 fp32 acc).
//   Combined tile (64x64) staged in LDS with XOR swizzle; W1 read via
//   wave-uniform (scalar) loads. z written to LDS zsh[64][36] (padded).
//
// Phase B (gates = sigmoid(z@W2 + b2); LSTM elementwise):
//   thread owns h-columns {2*tid, 2*tid+1}; its W2 slice (64 floats) is
//   preloaded into VGPRs AFTER phase A (keeps peak pressure < 128 VGPR).
//   Loops 64 rows: z row read from LDS (wave-uniform broadcast, no
//   conflicts), c read / h_new,c_new written as coalesced float2.
// ---------------------------------------------------------------------------
__global__ __launch_bounds__(256, 4)
void fused_qlstm(const float* __restrict__ x, const float* __restrict__ h,
                 const float* __restrict__ c,
                 const float* __restrict__ W1, const float* __restrict__ b1,
                 const float* __restrict__ W2, const float* __restrict__ b2,
                 float* __restrict__ out) {
    __shared__ __align__(16) float tile[64][64];  // 16 KB
    __shared__ __align__(16) float zsh[64][36];   // 9 KB, stride 36 floats (16B-aligned, bank-spread)

    const int tid     = threadIdx.x;
    const int lane    = tid & 63;
    const int g       = __builtin_amdgcn_readfirstlane(tid >> 6);  // wave id == gate
    const int rowbase = blockIdx.x * 64;

    // ---------------- Phase A ----------------
    float acc[8];
#pragma unroll
    for (int j = 0; j < 8; ++j) acc[j] = 0.0f;

    for (int kc = 0; kc < FAN1; kc += 64) {
        const float* src = (kc < IN_DIM) ? (x + kc) : (h + (kc - IN_DIM));

        __syncthreads();
#pragma unroll
        for (int i = 0; i < 4; ++i) {
            int idx = tid + 256 * i;
            int r   = idx >> 4;          // 0..63
            int kg  = idx & 15;          // float4 group
            float4 v = *(const float4*)(src + (size_t)(rowbase + r) * 512 + kg * 4);
            *(float4*)&tile[r][(kg ^ (r & 7)) << 2] = v;  // XOR swizzle
        }
        __syncthreads();

#pragma unroll 2
        for (int kg = 0; kg < 16; ++kg) {
            float4 cv = *(const float4*)&tile[lane][(kg ^ (lane & 7)) << 2];
#pragma unroll
            for (int j = 0; j < 8; ++j) {
                // wave-uniform address -> s_load_dwordx4
                float4 wv = *(const float4*)(W1 + (size_t)(g * 8 + j) * FAN1 + kc + kg * 4);
                acc[j] = fmaf(cv.x, wv.x, acc[j]);
                acc[j] = fmaf(cv.y, wv.y, acc[j]);
                acc[j] = fmaf(cv.z, wv.z, acc[j]);
                acc[j] = fmaf(cv.w, wv.w, acc[j]);
            }
        }
    }

    // z epilogue: bias + tanh -> LDS (wave g owns cols g*8..g*8+7, row=lane)
    {
        float o[8];
#pragma unroll
        for (int j = 0; j < 8; ++j)
            o[j] = tanh_fast(acc[j] + b1[g * 8 + j]);
        *(float4*)&zsh[lane][g * 8 + 0] = make_float4(o[0], o[1], o[2], o[3]);
        *(float4*)&zsh[lane][g * 8 + 4] = make_float4(o[4], o[5], o[6], o[7]);
    }

    // ---------------- Phase B ----------------
    // Preload W2/b2 for owned columns hh0=2*tid, hh1=2*tid+1 (after phase A
    // so acc[] registers are dead -> no spill).
    float  w2r[4][16];   // [gate][0..7]=col0 weights, [8..15]=col1 weights
    float2 b2r[4];
#pragma unroll
    for (int gg = 0; gg < 4; ++gg) {
        const float* wp = W2 + ((size_t)gg * HID_DIM + 2 * tid) * NQ;  // 16 consecutive floats
        float4 a = *(const float4*)(wp + 0);
        float4 b = *(const float4*)(wp + 4);
        float4 cc = *(const float4*)(wp + 8);
        float4 d = *(const float4*)(wp + 12);
        w2r[gg][0]  = a.x;  w2r[gg][1]  = a.y;  w2r[gg][2]  = a.z;  w2r[gg][3]  = a.w;
        w2r[gg][4]  = b.x;  w2r[gg][5]  = b.y;  w2r[gg][6]  = b.z;  w2r[gg][7]  = b.w;
        w2r[gg][8]  = cc.x; w2r[gg][9]  = cc.y; w2r[gg][10] = cc.z; w2r[gg][11] = cc.w;
        w2r[gg][12] = d.x;  w2r[gg][13] = d.y;  w2r[gg][14] = d.z;  w2r[gg][15] = d.w;
        b2r[gg] = *(const float2*)(b2 + gg * HID_DIM + 2 * tid);
    }

    __syncthreads();  // zsh fully written

    const size_t c_off = (size_t)B_TOTAL * HID_DIM;  // c_new offset in out

    for (int r = 0; r < 64; ++r) {
        const int row = rowbase + r;
        float2 cv = *(const float2*)(c + (size_t)row * HID_DIM + 2 * tid);

        float pre0[4], pre1[4];
#pragma unroll
        for (int gg = 0; gg < 4; ++gg) {
            // wave-uniform LDS address -> broadcast, conflict-free
            float4 za = *(const float4*)&zsh[r][gg * 8 + 0];
            float4 zb = *(const float4*)&zsh[r][gg * 8 + 4];
            float p0 = b2r[gg].x, p1 = b2r[gg].y;
            p0 = fmaf(za.x, w2r[gg][0], p0);  p1 = fmaf(za.x, w2r[gg][8],  p1);
            p0 = fmaf(za.y, w2r[gg][1], p0);  p1 = fmaf(za.y, w2r[gg][9],  p1);
            p0 = fmaf(za.z, w2r[gg][2], p0);  p1 = fmaf(za.z, w2r[gg][10], p1);
            p0 = fmaf(za.w, w2r[gg][3], p0);  p1 = fmaf(za.w, w2r[gg][11], p1);
            p0 = fmaf(zb.x, w2r[gg][4], p0);  p1 = fmaf(zb.x, w2r[gg][12], p1);
            p0 = fmaf(zb.y, w2r[gg][5], p0);  p1 = fmaf(zb.y, w2r[gg][13], p1);
            p0 = fmaf(zb.z, w2r[gg][6], p0);  p1 = fmaf(zb.z, w2r[gg][14], p1);
            p0 = fmaf(zb.w, w2r[gg][7], p0);  p1 = fmaf(zb.w, w2r[gg][15], p1);
            pre0[gg] = p0;
            pre1[gg] = p1;
        }

        float i0 = sigmoid_f(pre0[0]), i1 = sigmoid_f(pre1[0]);
        float f0 = sigmoid_f(pre0[1]), f1 = sigmoid_f(pre1[1]);
        float o0 = sigmoid_f(pre0[2]), o1 = sigmoid_f(pre1[2]);
        float g0 = sigmoid_f(pre0[3]), g1 = sigmoid_f(pre1[3]);

        float cn0 = f0 * cv.x + i0 * g0;
        float cn1 = f1 * cv.y + i1 * g1;
        float hn0 = o0 * tanh_fast(cn0);
        float hn1 = o1 * tanh_fast(cn1);

        *(float2*)(out + (size_t)row * HID_DIM + 2 * tid)         = make_float2(hn0, hn1);
        *(float2*)(out + c_off + (size_t)row * HID_DIM + 2 * tid) = make_float2(cn0, cn1);
    }
}

extern "C" void kernel_launch(void* const* d_in, const int* in_sizes, int n_in,
                              void* d_out, int out_size, void* d_ws, size_t ws_size,
                              hipStream_t stream) {
    const float* x  = (const float*)d_in[0];
    const float* h  = (const float*)d_in[1];
    const float* c  = (const float*)d_in[2];
    const float* W1 = (const float*)d_in[3];
    const float* b1 = (const float*)d_in[4];
    const float* W2 = (const float*)d_in[5];
    const float* b2 = (const float*)d_in[6];
    float* out = (float*)d_out;

    hipLaunchKernelGGL(fused_qlstm, dim3(B_TOTAL / 64), dim3(256), 0, stream,
                       x, h, c, W1, b1, W2, b2, out);
}